// Round 1
// baseline (301.452 us; speedup 1.0000x reference)
//
#include <hip/hip_runtime.h>

#define SS 2048
#define DD 64

typedef __attribute__((ext_vector_type(8))) short bf16x8;
typedef __attribute__((ext_vector_type(4))) float f32x4;

__device__ inline short f2bf(float f) {
    unsigned u = __builtin_bit_cast(unsigned, f);
    u += 0x7fffu + ((u >> 16) & 1u);   // round-to-nearest-even
    return (short)(u >> 16);
}

__global__ __launch_bounds__(256) void pattn_kernel(
    const float* __restrict__ q, const float* __restrict__ k,
    const float* __restrict__ v, float* __restrict__ out,
    float* __restrict__ attn)
{
    const int bh  = blockIdx.x >> 5;   // 0..31  (B*H)
    const int qt  = blockIdx.x & 31;   // 0..31  (q tile of 64)
    const int tid = threadIdx.x;
    const int wid  = tid >> 6;
    const int lane = tid & 63;
    const int col  = lane & 15;
    const int g    = lane >> 4;

    const long hoff = (long)bh * SS * DD;
    const int  q0   = qt * 64;
    const int  qrowA = q0 + wid * 16 + col;     // A-fragment row (q index)
    const int  qrowC = q0 + wid * 16 + 4 * g;   // C-layout row base

    __shared__ __align__(16) short Kl[32][72];   // [key][d], pad 64->72
    __shared__ __align__(16) short Vt[64][40];   // [d][key], pad 32->40
    __shared__ __align__(16) short Wl[4][16][40];// per wave [q][key]

    // Q fragments: A[row=lane&15][kdim = 8*g + i], two d-halves
    bf16x8 aq0, aq1;
    {
        const float* qp = q + hoff + (long)qrowA * DD + 8 * g;
        #pragma unroll
        for (int i = 0; i < 8; ++i) aq0[i] = f2bf(qp[i]);
        #pragma unroll
        for (int i = 0; i < 8; ++i) aq1[i] = f2bf(qp[32 + i]);
    }

    const float SCALE2 = 0.125f * 1.4426950408889634f;  // (1/sqrt(64))*log2(e)

    // ---------------- pass 1: row sums of exp(scores) ----------------
    float lsum[4] = {0.f, 0.f, 0.f, 0.f};

    for (int k0 = 0; k0 < SS; k0 += 32) {
        {   // stage K chunk -> LDS bf16
            int key = tid >> 3, dq = (tid & 7) << 3;
            const float* kp = k + hoff + (long)(k0 + key) * DD + dq;
            bf16x8 pk;
            #pragma unroll
            for (int i = 0; i < 8; ++i) pk[i] = f2bf(kp[i]);
            *reinterpret_cast<bf16x8*>(&Kl[key][dq]) = pk;
        }
        __syncthreads();
        #pragma unroll
        for (int t16 = 0; t16 < 2; ++t16) {
            const short* kr = &Kl[t16 * 16 + col][0];
            bf16x8 kb0 = *reinterpret_cast<const bf16x8*>(kr + 8 * g);
            bf16x8 kb1 = *reinterpret_cast<const bf16x8*>(kr + 32 + 8 * g);
            f32x4 c = {0.f, 0.f, 0.f, 0.f};
            c = __builtin_amdgcn_mfma_f32_16x16x32_bf16(aq0, kb0, c, 0, 0, 0);
            c = __builtin_amdgcn_mfma_f32_16x16x32_bf16(aq1, kb1, c, 0, 0, 0);
            #pragma unroll
            for (int r = 0; r < 4; ++r)
                lsum[r] += exp2f(c[r] * SCALE2);
        }
        __syncthreads();
    }
    #pragma unroll
    for (int m = 1; m <= 8; m <<= 1) {
        #pragma unroll
        for (int r = 0; r < 4; ++r)
            lsum[r] += __shfl_xor(lsum[r], m, 64);
    }
    float invl[4];
    #pragma unroll
    for (int r = 0; r < 4; ++r) invl[r] = 1.0f / lsum[r];

    // ---------------- pass 2: weights out + PV ----------------
    f32x4 acc[4];
    #pragma unroll
    for (int d = 0; d < 4; ++d) acc[d] = (f32x4){0.f, 0.f, 0.f, 0.f};

    float* attnb = attn + (long)bh * SS * SS;

    for (int k0 = 0; k0 < SS; k0 += 32) {
        {   // stage K chunk
            int key = tid >> 3, dq = (tid & 7) << 3;
            const float* kp = k + hoff + (long)(k0 + key) * DD + dq;
            bf16x8 pk;
            #pragma unroll
            for (int i = 0; i < 8; ++i) pk[i] = f2bf(kp[i]);
            *reinterpret_cast<bf16x8*>(&Kl[key][dq]) = pk;
        }
        {   // stage V chunk transposed -> Vt[d][key]
            int key = tid & 31, dq = (tid >> 5) << 3;
            const float* vp = v + hoff + (long)(k0 + key) * DD + dq;
            #pragma unroll
            for (int j = 0; j < 8; ++j) Vt[dq + j][key] = f2bf(vp[j]);
        }
        __syncthreads();

        #pragma unroll
        for (int t16 = 0; t16 < 2; ++t16) {
            const short* kr = &Kl[t16 * 16 + col][0];
            bf16x8 kb0 = *reinterpret_cast<const bf16x8*>(kr + 8 * g);
            bf16x8 kb1 = *reinterpret_cast<const bf16x8*>(kr + 32 + 8 * g);
            f32x4 c = {0.f, 0.f, 0.f, 0.f};
            c = __builtin_amdgcn_mfma_f32_16x16x32_bf16(aq0, kb0, c, 0, 0, 0);
            c = __builtin_amdgcn_mfma_f32_16x16x32_bf16(aq1, kb1, c, 0, 0, 0);
            #pragma unroll
            for (int r = 0; r < 4; ++r) {
                float w = exp2f(c[r] * SCALE2) * invl[r];
                attnb[(long)(qrowC + r) * SS + k0 + t16 * 16 + col] = w;
                Wl[wid][4 * g + r][t16 * 16 + col] = f2bf(w);
            }
        }
        __syncthreads();   // W tile ready

        // PV: A = W[q=lane&15][key=8g+i], B = V[key][d] from Vt
        {
            bf16x8 wa = *reinterpret_cast<const bf16x8*>(&Wl[wid][col][8 * g]);
            #pragma unroll
            for (int ds = 0; ds < 4; ++ds) {
                bf16x8 vb = *reinterpret_cast<const bf16x8*>(&Vt[ds * 16 + col][8 * g]);
                acc[ds] = __builtin_amdgcn_mfma_f32_16x16x32_bf16(wa, vb, acc[ds], 0, 0, 0);
            }
        }
        __syncthreads();   // before restaging Kl/Vt
    }

    // ---------------- row-norm preconditioning + output ----------------
    float ssq[4] = {0.f, 0.f, 0.f, 0.f};
    #pragma unroll
    for (int ds = 0; ds < 4; ++ds)
        #pragma unroll
        for (int r = 0; r < 4; ++r)
            ssq[r] += acc[ds][r] * acc[ds][r];
    #pragma unroll
    for (int m = 1; m <= 8; m <<= 1) {
        #pragma unroll
        for (int r = 0; r < 4; ++r)
            ssq[r] += __shfl_xor(ssq[r], m, 64);
    }
    #pragma unroll
    for (int r = 0; r < 4; ++r) {
        float inv = 1.0f / (sqrtf(ssq[r]) + 1e-8f);
        #pragma unroll
        for (int ds = 0; ds < 4; ++ds)
            out[hoff + (long)(qrowC + r) * DD + ds * 16 + col] = acc[ds][r] * inv;
    }
}

extern "C" void kernel_launch(void* const* d_in, const int* in_sizes, int n_in,
                              void* d_out, int out_size, void* d_ws, size_t ws_size,
                              hipStream_t stream) {
    const float* q = (const float*)d_in[0];
    const float* k = (const float*)d_in[1];
    const float* v = (const float*)d_in[2];
    float* out  = (float*)d_out;
    float* attn = out + (long)2 * 16 * SS * DD;   // second tuple element
    dim3 grid(1024), block(256);
    hipLaunchKernelGGL(pattn_kernel, grid, block, 0, stream, q, k, v, out, attn);
}